// Round 6
// baseline (326.809 us; speedup 1.0000x reference)
//
#include <hip/hip_runtime.h>
#include <hip/hip_bf16.h>

// ---------------------------------------------------------------------------
// LucasKANLayer fused: y[b,o] = sum_i sum_d L_d(tanh(x[b,i])) * C[i,o,d]
// R17 = R11 EXACT formulas (16x16x32, dbuf global_load_lds, XOR swizzle,
// __syncthreads/step - verified 137us) with BN 128 -> 64 to cut LDS to
// 20 KB -> EXACTLY 8 blocks/CU (163840/20480), 32 waves/CU (HW max).
// Theory: R11's limiter is latency (matrix pipe idle 53% while waves wait
// on lgkmcnt/barrier/lucas chains), NOT issue bandwidth (m114: MFMA+VALU
// are separate pipes). Occupancy tracked perf monotonically across
// R11/R13/R14/R16; LDS (36KB x 4 = 144KB) was the occupancy cap, VGPR=56
// allows 8 waves/SIMD. Halving BN doubles blocks: grid (16,64,2) = 2048.
// Lucas/MFMA doubles (4 frags/16 MFMA) but VALU pipe stays sub-critical
// (1280 vs 2048 matrix-cyc per 8-wave window).
// R15/R16 lesson kept in notes: 32x32 shape loses even conflict-free.
// ---------------------------------------------------------------------------

typedef __attribute__((ext_vector_type(8)))  short  short8;    // bf16x8 MFMA frag
typedef __attribute__((ext_vector_type(4)))  unsigned short ushort4v;
typedef __attribute__((ext_vector_type(8)))  unsigned short ushort8;
typedef __attribute__((ext_vector_type(4)))  float  float4v;
typedef __attribute__((ext_vector_type(4)))  unsigned int uint4v;

#define M_DIM 8192
#define I_DIM 1024
#define O_DIM 1024
#define K_DIM 8192   // I_DIM * 8
#define BM 128
#define BN 64
#define BK 64        // 8 i-values per K-step
#define KSPLIT 2
#define KHALF (K_DIM / KSPLIT)
#define NSTEP (KHALF / BK)   // 64

// round-to-nearest-even fp32 -> bf16 bits (prep kernels)
__device__ __forceinline__ unsigned short f2bf(float f) {
    unsigned int u = __float_as_uint(f);
    u += 0x7FFFu + ((u >> 16) & 1u);
    return (unsigned short)(u >> 16);
}

// ---- P1: zero d_out + tanh->T, grid-stride, NO LDS (full occupancy) ----
// T[b][group g]: slot 2p = t(i=g*8+p), slot 2p+1 = t(i=g*8+p+4)  [R6-verified].
__global__ __launch_bounds__(256) void prep_zt_kernel(const float* __restrict__ x,
                                                      unsigned short* __restrict__ T,
                                                      float* __restrict__ outz) {
    const int nthr = gridDim.x * 256;
    const int gid  = blockIdx.x * 256 + threadIdx.x;

    const int zN = (M_DIM * O_DIM) / 4;
    const float4v z = {0.f, 0.f, 0.f, 0.f};
    for (int i = gid; i < zN; i += nthr)
        *(float4v*)(outz + (size_t)i * 4) = z;

    const int tN = (M_DIM * I_DIM) / 8;
    for (int i = gid; i < tN; i += nthr) {
        const size_t idx = (size_t)i * 8;
        float4v v0 = *(const float4v*)(x + idx);
        float4v v1 = *(const float4v*)(x + idx + 4);
        unsigned short t[8];
        t[0] = f2bf(tanhf(v0[0])); t[1] = f2bf(tanhf(v0[1]));
        t[2] = f2bf(tanhf(v0[2])); t[3] = f2bf(tanhf(v0[3]));
        t[4] = f2bf(tanhf(v1[0])); t[5] = f2bf(tanhf(v1[1]));
        t[6] = f2bf(tanhf(v1[2])); t[7] = f2bf(tanhf(v1[3]));
        ushort8 o;
        #pragma unroll
        for (int p = 0; p < 4; ++p) { o[2 * p] = t[p]; o[2 * p + 1] = t[p + 4]; }
        *(ushort8*)(T + idx) = o;
    }
}

// ---- P2: B transpose via LDS (tile 64 i x 32 o, coalesced R+W) ----
// Bt[o][i*8+d] = bf16(coeffs[i][o][d])                     [R9-verified].
__global__ __launch_bounds__(256) void prep_tr_kernel(const float* __restrict__ c,
                                                      unsigned short* __restrict__ Bt) {
    __shared__ unsigned short S[32][64 * 8 + 8];
    const int tid = threadIdx.x;
    const int tb  = blockIdx.x;                    // 0..511
    const int i0 = (tb >> 5) * 64;
    const int o0 = (tb & 31) * 32;
    #pragma unroll 4
    for (int p = 0; p < 16; ++p) {
        const int il = p * 4 + (tid >> 6);
        const int e  = (tid & 63) * 4;
        const float* src = c + (size_t)(i0 + il) * 8192 + o0 * 8 + e;
        float4v v = *(const float4v*)src;
        ushort4v u;
        u[0] = f2bf(v[0]); u[1] = f2bf(v[1]); u[2] = f2bf(v[2]); u[3] = f2bf(v[3]);
        *(ushort4v*)&S[e >> 3][il * 8 + (e & 7)] = u;
    }
    __syncthreads();
    #pragma unroll 4
    for (int q = 0; q < 16; ++q) {
        const int ol = q * 2 + (tid >> 7);
        const int ch = (tid & 127) * 4;
        ushort4v u = *(const ushort4v*)&S[ol][ch];
        *(ushort4v*)(Bt + (size_t)(o0 + ol) * K_DIM + i0 * 8 + ch) = u;
    }
}

// Lucas A-fragment {2, t, L2..L7} packed bf16x8 from bf16 t-bits tb (low 16).
__device__ __forceinline__ short8 lucas_frag(unsigned int tb) {
    const float t = __uint_as_float(tb << 16);
    const float L2v = fmaf(t, t, 2.0f);
    const float L3v = fmaf(t, L2v, t);
    const float L4v = fmaf(t, L3v, L2v);
    const float L5v = fmaf(t, L4v, L3v);
    const float L6v = fmaf(t, L5v, L4v);
    const float L7v = fmaf(t, L6v, L5v);
    union { uint4v u; short8 s; } r;
#if __has_builtin(__builtin_amdgcn_cvt_pk_bf16_f32)
    {
        auto p0 = __builtin_amdgcn_cvt_pk_bf16_f32(2.0f, t);
        auto p1 = __builtin_amdgcn_cvt_pk_bf16_f32(L2v, L3v);
        auto p2 = __builtin_amdgcn_cvt_pk_bf16_f32(L4v, L5v);
        auto p3 = __builtin_amdgcn_cvt_pk_bf16_f32(L6v, L7v);
        __builtin_memcpy(&r.u[0], &p0, 4);
        __builtin_memcpy(&r.u[1], &p1, 4);
        __builtin_memcpy(&r.u[2], &p2, 4);
        __builtin_memcpy(&r.u[3], &p3, 4);
    }
#else
    {
        r.u[0] = 0x4000u | (tb << 16);
        r.u[1] = __builtin_amdgcn_perm(__float_as_uint(L3v), __float_as_uint(L2v), 0x07060302);
        r.u[2] = __builtin_amdgcn_perm(__float_as_uint(L5v), __float_as_uint(L4v), 0x07060302);
        r.u[3] = __builtin_amdgcn_perm(__float_as_uint(L7v), __float_as_uint(L6v), 0x07060302);
    }
#endif
    return r.s;
}

// ---- fused GEMM: out[m][n] += sum_{k half} A[m][k] * Bt[n][k] ----
// R17: 4 waves of 32m x 64n, 8 blocks/CU (20 KB LDS), R11 formulas.
__global__ __launch_bounds__(256, 8) void gemm_kernel(const unsigned short* __restrict__ T,
                                                      const unsigned short* __restrict__ Bt,
                                                      float* __restrict__ out) {
    __shared__ unsigned short Bs[2][BN * BK];   // 16 KB, XOR-swizzled, dbuf
    __shared__ unsigned short Ts[2][BM * 8];    // 4 KB, dbuf (permuted 8-groups)

    const int tid  = threadIdx.x;
    const int lane = tid & 63;
    const int wave = tid >> 6;
    const int n0 = blockIdx.x * BN;        // x = n-panel (16): XCD = linear%8 = x%8
    const int m0 = blockIdx.y * BM;        // y = m (64)
    const int k0 = blockIdx.z * KHALF;     // z = K half (2)

    const int wm0  = wave * 32;            // wave tile 32m x 64n
    const int l16  = lane & 15;
    const int quad = lane >> 4;

    const int srow   = lane >> 3;          // staging: 0..7
    const int il     = lane & 7;
    const int gchunk = il ^ srow;          // XOR-swizzled global 16B chunk

    float4v acc[2][4];
    const float4v zero = {0.f, 0.f, 0.f, 0.f};
    #pragma unroll
    for (int a = 0; a < 2; ++a)
        #pragma unroll
        for (int b = 0; b < 4; ++b) acc[a][b] = zero;

    // stage one K-step: B 2 insts/wave (8 rows each, 64 total), T wave<2
    auto stage = [&](int buf, int kt) {
        #pragma unroll
        for (int r = 0; r < 2; ++r) {
            const int rowb = r * 32 + wave * 8;
            const unsigned short* gB = Bt + (size_t)(n0 + rowb + srow) * K_DIM + kt + gchunk * 8;
            __builtin_amdgcn_global_load_lds(
                (const __attribute__((address_space(1))) unsigned int*)gB,
                (__attribute__((address_space(3))) unsigned int*)&Bs[buf][rowb * BK], 16, 0, 0);
        }
        if (wave < 2) {
            const unsigned short* gT = T + (size_t)(m0 + wave * 64 + lane) * I_DIM + kt / 8;
            __builtin_amdgcn_global_load_lds(
                (const __attribute__((address_space(1))) unsigned int*)gT,
                (__attribute__((address_space(3))) unsigned int*)&Ts[buf][wave * 64 * 8], 16, 0, 0);
        }
    };

    stage(0, k0);
    __syncthreads();

    int cur = 0;
    for (int s = 0; s < NSTEP; ++s) {
        const int nxt = cur ^ 1;
        if (s + 1 < NSTEP) stage(nxt, k0 + (s + 1) * BK);

        // t-words: one b32 per m-tile {lo=t(quad)->k2=0, hi=t(quad+4)->k2=1}
        unsigned int tw[2];
        #pragma unroll
        for (int tt = 0; tt < 2; ++tt)
            tw[tt] = *(const unsigned int*)&Ts[cur][(wm0 + tt * 16 + l16) * 8 + quad * 2];

        #pragma unroll
        for (int k2 = 0; k2 < 2; ++k2) {
            short8 af[2];
            af[0] = lucas_frag(k2 ? (tw[0] >> 16) : (tw[0] & 0xffffu));
            af[1] = lucas_frag(k2 ? (tw[1] >> 16) : (tw[1] & 0xffffu));
            short8 bfr[4];
            #pragma unroll
            for (int j = 0; j < 4; ++j) {
                const int brow = j * 16 + l16;
                bfr[j] = *(const short8*)&Bs[cur][brow * BK + (((k2 * 4 + quad) ^ (l16 & 7)) * 8)];
            }
            #pragma unroll
            for (int tt = 0; tt < 2; ++tt)
                #pragma unroll
                for (int j = 0; j < 4; ++j)
                    acc[tt][j] = __builtin_amdgcn_mfma_f32_16x16x32_bf16(
                        af[tt], bfr[j], acc[tt][j], 0, 0, 0);
        }

        __syncthreads();   // drains prefetch + protects Bs/Ts swap
        cur = nxt;
    }

    // epilogue: D[row=(lane>>4)*4+r][col=lane&15] (verified R1-R9)
    #pragma unroll
    for (int tt = 0; tt < 2; ++tt) {
        #pragma unroll
        for (int tn = 0; tn < 4; ++tn) {
            const int col = n0 + tn * 16 + l16;
            #pragma unroll
            for (int r = 0; r < 4; ++r) {
                const int row = m0 + wm0 + tt * 16 + quad * 4 + r;
                atomicAdd(&out[(size_t)row * O_DIM + col], acc[tt][tn][r]);
            }
        }
    }
}

// ---- fallback (tiny workspace): direct fp32 ----
__global__ __launch_bounds__(256) void naive_kernel(const float* __restrict__ x,
                                                    const float* __restrict__ c,
                                                    float* __restrict__ out) {
    int idx = blockIdx.x * 256 + threadIdx.x;   // one (b,o)
    int b = idx >> 10;
    int o = idx & 1023;
    const float* xb = x + (size_t)b * I_DIM;
    float acc = 0.f;
    for (int i = 0; i < I_DIM; ++i) {
        float t = tanhf(xb[i]);
        float L[8];
        L[0] = 2.0f; L[1] = t;
        #pragma unroll
        for (int d = 2; d < 8; ++d) L[d] = t * L[d - 1] + L[d - 2];
        const float* cc = c + (size_t)i * 8192 + o * 8;
        #pragma unroll
        for (int d = 0; d < 8; ++d) acc += L[d] * cc[d];
    }
    out[idx] = acc;
}

extern "C" void kernel_launch(void* const* d_in, const int* in_sizes, int n_in,
                              void* d_out, int out_size, void* d_ws, size_t ws_size,
                              hipStream_t stream) {
    const float* x      = (const float*)d_in[0];
    const float* coeffs = (const float*)d_in[1];
    float* out = (float*)d_out;

    const size_t btBytes = (size_t)O_DIM * K_DIM * sizeof(unsigned short);   // 16 MiB
    const size_t tBytes  = (size_t)M_DIM * I_DIM * sizeof(unsigned short);   // 16 MiB

    if (ws_size >= btBytes + tBytes) {
        unsigned short* Bt = (unsigned short*)d_ws;
        unsigned short* T  = (unsigned short*)((char*)d_ws + btBytes);

        const int xBlocks = (I_DIM / 64) * (I_DIM / 32);   // 512 transpose tiles
        prep_tr_kernel<<<xBlocks, 256, 0, stream>>>(coeffs, Bt);
        prep_zt_kernel<<<2048, 256, 0, stream>>>(x, T, out);

        dim3 grid(O_DIM / BN, M_DIM / BM, KSPLIT);   // (16, 64, 2): XCD = x%8
        gemm_kernel<<<grid, 256, 0, stream>>>(T, Bt, out);
    } else {
        naive_kernel<<<(M_DIM * O_DIM) / 256, 256, 0, stream>>>(x, coeffs, out);
    }
}

// Round 7
// 281.941 us; speedup vs baseline: 1.1591x; 1.1591x over previous
//
#include <hip/hip_runtime.h>
#include <hip/hip_bf16.h>

// ---------------------------------------------------------------------------
// LucasKANLayer fused: y[b,o] = sum_i sum_d L_d(tanh(x[b,i])) * C[i,o,d]
// R18 = 8-phase-style 256x256 deep-pipeline port (m201 template, T2+T3+T4+T5):
//   - Ledger: R11 (128x128, 2-phase, 4 blk/CU) = 137us is the verified best;
//     R13 (fat waves), R14 (counted vmcnt @2blk/CU), R15/R16 (32x32 shape),
//     R17 (BN=64 high-TLP) ALL regressed. Occupancy/TLP is NOT the lever
//     (R17: occ 79%, Mfma 26). The documented next rung is the 256^2
//     fine-interleaved schedule at 1 blk/CU with counted vmcnt.
//   - 512 thr (8 waves 2m x 4n), wave tile 128m x 64n, acc[8][4].
//   - LDS 4 buffers x (Bs 32K + Ts 4K) = 144 KiB, 1 block/CU.
//   - Stage distance 2: step s issues tile s+2 into buf (s+2)&3 (!= cur,
//     != s+1; last readers of that buf finished before step s-1's entry
//     barrier). Entry wait: vmcnt(5)/(4) (one tile in flight), never 0
//     until tail.
//   - 4 phases/step (k2,mhalf): {ds_reads + staged-gload portion -> barrier
//     -> setprio(1) lucas+16 MFMA setprio(0) -> barrier}.
//   All data-layout formulas (B XOR swizzle, permuted-T packing, lucas i =
//   k2*4+quad hi/lo selection, 16x16 C/D epilogue) verified in R11/R15.
// Kill-criterion: fail or gemm >= 140us -> revert R11, declare ceiling.
// ---------------------------------------------------------------------------

typedef __attribute__((ext_vector_type(8)))  short  short8;    // bf16x8 MFMA frag
typedef __attribute__((ext_vector_type(4)))  unsigned short ushort4v;
typedef __attribute__((ext_vector_type(8)))  unsigned short ushort8;
typedef __attribute__((ext_vector_type(4)))  float  float4v;
typedef __attribute__((ext_vector_type(4)))  unsigned int uint4v;

#define M_DIM 8192
#define I_DIM 1024
#define O_DIM 1024
#define K_DIM 8192   // I_DIM * 8
#define BM 256
#define BN 256
#define BK 64        // 8 i-values per K-step
#define KSPLIT 2
#define KHALF (K_DIM / KSPLIT)
#define NSTEP (KHALF / BK)   // 64

// round-to-nearest-even fp32 -> bf16 bits (prep kernels)
__device__ __forceinline__ unsigned short f2bf(float f) {
    unsigned int u = __float_as_uint(f);
    u += 0x7FFFu + ((u >> 16) & 1u);
    return (unsigned short)(u >> 16);
}

// ---- P1: zero d_out + tanh->T, grid-stride, NO LDS (full occupancy) ----
// T[b][group g]: slot 2p = t(i=g*8+p), slot 2p+1 = t(i=g*8+p+4)  [R6-verified].
__global__ __launch_bounds__(256) void prep_zt_kernel(const float* __restrict__ x,
                                                      unsigned short* __restrict__ T,
                                                      float* __restrict__ outz) {
    const int nthr = gridDim.x * 256;
    const int gid  = blockIdx.x * 256 + threadIdx.x;

    const int zN = (M_DIM * O_DIM) / 4;
    const float4v z = {0.f, 0.f, 0.f, 0.f};
    for (int i = gid; i < zN; i += nthr)
        *(float4v*)(outz + (size_t)i * 4) = z;

    const int tN = (M_DIM * I_DIM) / 8;
    for (int i = gid; i < tN; i += nthr) {
        const size_t idx = (size_t)i * 8;
        float4v v0 = *(const float4v*)(x + idx);
        float4v v1 = *(const float4v*)(x + idx + 4);
        unsigned short t[8];
        t[0] = f2bf(tanhf(v0[0])); t[1] = f2bf(tanhf(v0[1]));
        t[2] = f2bf(tanhf(v0[2])); t[3] = f2bf(tanhf(v0[3]));
        t[4] = f2bf(tanhf(v1[0])); t[5] = f2bf(tanhf(v1[1]));
        t[6] = f2bf(tanhf(v1[2])); t[7] = f2bf(tanhf(v1[3]));
        ushort8 o;
        #pragma unroll
        for (int p = 0; p < 4; ++p) { o[2 * p] = t[p]; o[2 * p + 1] = t[p + 4]; }
        *(ushort8*)(T + idx) = o;
    }
}

// ---- P2: B transpose via LDS (tile 64 i x 32 o, coalesced R+W) ----
// Bt[o][i*8+d] = bf16(coeffs[i][o][d])                     [R9-verified].
__global__ __launch_bounds__(256) void prep_tr_kernel(const float* __restrict__ c,
                                                      unsigned short* __restrict__ Bt) {
    __shared__ unsigned short S[32][64 * 8 + 8];
    const int tid = threadIdx.x;
    const int tb  = blockIdx.x;                    // 0..511
    const int i0 = (tb >> 5) * 64;
    const int o0 = (tb & 31) * 32;
    #pragma unroll 4
    for (int p = 0; p < 16; ++p) {
        const int il = p * 4 + (tid >> 6);
        const int e  = (tid & 63) * 4;
        const float* src = c + (size_t)(i0 + il) * 8192 + o0 * 8 + e;
        float4v v = *(const float4v*)src;
        ushort4v u;
        u[0] = f2bf(v[0]); u[1] = f2bf(v[1]); u[2] = f2bf(v[2]); u[3] = f2bf(v[3]);
        *(ushort4v*)&S[e >> 3][il * 8 + (e & 7)] = u;
    }
    __syncthreads();
    #pragma unroll 4
    for (int q = 0; q < 16; ++q) {
        const int ol = q * 2 + (tid >> 7);
        const int ch = (tid & 127) * 4;
        ushort4v u = *(const ushort4v*)&S[ol][ch];
        *(ushort4v*)(Bt + (size_t)(o0 + ol) * K_DIM + i0 * 8 + ch) = u;
    }
}

// Lucas A-fragment {2, t, L2..L7} packed bf16x8 from bf16 t-bits tb (low 16).
__device__ __forceinline__ short8 lucas_frag(unsigned int tb) {
    const float t = __uint_as_float(tb << 16);
    const float L2v = fmaf(t, t, 2.0f);
    const float L3v = fmaf(t, L2v, t);
    const float L4v = fmaf(t, L3v, L2v);
    const float L5v = fmaf(t, L4v, L3v);
    const float L6v = fmaf(t, L5v, L4v);
    const float L7v = fmaf(t, L6v, L5v);
    union { uint4v u; short8 s; } r;
#if __has_builtin(__builtin_amdgcn_cvt_pk_bf16_f32)
    {
        auto p0 = __builtin_amdgcn_cvt_pk_bf16_f32(2.0f, t);
        auto p1 = __builtin_amdgcn_cvt_pk_bf16_f32(L2v, L3v);
        auto p2 = __builtin_amdgcn_cvt_pk_bf16_f32(L4v, L5v);
        auto p3 = __builtin_amdgcn_cvt_pk_bf16_f32(L6v, L7v);
        __builtin_memcpy(&r.u[0], &p0, 4);
        __builtin_memcpy(&r.u[1], &p1, 4);
        __builtin_memcpy(&r.u[2], &p2, 4);
        __builtin_memcpy(&r.u[3], &p3, 4);
    }
#else
    {
        r.u[0] = 0x4000u | (tb << 16);
        r.u[1] = __builtin_amdgcn_perm(__float_as_uint(L3v), __float_as_uint(L2v), 0x07060302);
        r.u[2] = __builtin_amdgcn_perm(__float_as_uint(L5v), __float_as_uint(L4v), 0x07060302);
        r.u[3] = __builtin_amdgcn_perm(__float_as_uint(L7v), __float_as_uint(L6v), 0x07060302);
    }
#endif
    return r.s;
}

// ---- fused GEMM: out[m][n] += sum_{k half} A[m][k] * Bt[n][k] ----
// R18: 256x256 tile, 8 waves (2m x 4n), wave tile 128m x 64n, 4-deep
// staging with counted vmcnt, 4 fine-interleaved phases per K-step.
__global__ __launch_bounds__(512, 2) void gemm_kernel(const unsigned short* __restrict__ T,
                                                      const unsigned short* __restrict__ Bt,
                                                      float* __restrict__ out) {
    __shared__ unsigned short Bs[4][BN * BK];   // 4 x 32 KB, XOR-swizzled
    __shared__ unsigned short Ts[4][BM * 8];    // 4 x 4 KB (permuted 8-groups)

    const int tid  = threadIdx.x;
    const int lane = tid & 63;
    const int wave = tid >> 6;             // 0..7
    const int wm = wave >> 2;              // 0..1: m-half of block tile
    const int wn = wave & 3;               // 0..3: n-quarter
    const int n0 = blockIdx.x * BN;        // x = n-panel (4)
    const int m0 = blockIdx.y * BM;        // y = m (32)
    const int k0 = blockIdx.z * KHALF;     // z = K half (2)

    const int l16  = lane & 15;
    const int quad = lane >> 4;

    const int srow   = lane >> 3;          // staging: 0..7
    const int il     = lane & 7;
    const int gchunk = il ^ srow;          // XOR-swizzled global 16B chunk

    float4v acc[8][4];
    const float4v zero = {0.f, 0.f, 0.f, 0.f};
    #pragma unroll
    for (int a = 0; a < 8; ++a)
        #pragma unroll
        for (int b = 0; b < 4; ++b) acc[a][b] = zero;

    // B staging: 8 waves x 32 rows each = 256 rows; 4 insts/wave in 2 parts.
    auto stageB = [&](int buf, int kt, int part) {
        #pragma unroll
        for (int r = part * 2; r < part * 2 + 2; ++r) {
            const int rowb = wave * 32 + r * 8;
            const unsigned short* gB = Bt + (size_t)(n0 + rowb + srow) * K_DIM + kt + gchunk * 8;
            __builtin_amdgcn_global_load_lds(
                (const __attribute__((address_space(1))) unsigned int*)gB,
                (__attribute__((address_space(3))) unsigned int*)&Bs[buf][rowb * BK], 16, 0, 0);
        }
    };
    // T staging: waves 0-3 x 64 rows = 256 rows, 1 inst/wave.
    auto stageT = [&](int buf, int kt) {
        if (wave < 4) {
            const unsigned short* gT = T + (size_t)(m0 + wave * 64 + lane) * I_DIM + kt / 8;
            __builtin_amdgcn_global_load_lds(
                (const __attribute__((address_space(1))) unsigned int*)gT,
                (__attribute__((address_space(3))) unsigned int*)&Ts[buf][wave * 64 * 8], 16, 0, 0);
        }
    };
    // per-tile loads/wave: waves 0-3 -> 5, waves 4-7 -> 4.

    // prologue: tiles 0 and 1 issued (2 tiles in flight)
    stageB(0, k0, 0); stageB(0, k0, 1); stageT(0, k0);
    stageB(1, k0 + BK, 0); stageB(1, k0 + BK, 1); stageT(1, k0 + BK);

    for (int s = 0; s < NSTEP; ++s) {
        const int cur  = s & 3;
        const int pre  = (s + 2) & 3;
        const int kpre = k0 + (s + 2) * BK;
        const bool do_pre = (s + 2 < NSTEP);

        // entry: tile s landed (one tile stays in flight, except tail)
        if (s + 1 < NSTEP) {
            if (wave < 4) asm volatile("s_waitcnt vmcnt(5)" ::: "memory");
            else          asm volatile("s_waitcnt vmcnt(4)" ::: "memory");
        } else {
            asm volatile("s_waitcnt vmcnt(0)" ::: "memory");
        }
        __builtin_amdgcn_s_barrier();

        short8 bfr[4];
        #pragma unroll
        for (int p = 0; p < 4; ++p) {
            const int k2 = p >> 1;     // k-half within K-step
            const int mh = p & 1;      // m-half within wave tile
            if (mh == 0) {             // B-frags live across 2 phases
                #pragma unroll
                for (int nt = 0; nt < 4; ++nt) {
                    const int brow = wn * 64 + nt * 16 + l16;
                    bfr[nt] = *(const short8*)
                        &Bs[cur][brow * BK + (((k2 * 4 + quad) ^ (l16 & 7)) * 8)];
                }
            }
            unsigned int tw[4];
            #pragma unroll
            for (int mt = 0; mt < 4; ++mt) {
                const int mrow = wm * 128 + mh * 64 + mt * 16 + l16;
                tw[mt] = *(const unsigned int*)&Ts[cur][mrow * 8 + quad * 2];
            }
            if (do_pre) {
                if (p == 0)      stageB(pre, kpre, 0);
                else if (p == 1) stageB(pre, kpre, 1);
                else if (p == 2) stageT(pre, kpre);
            }
            __builtin_amdgcn_s_barrier();
            __builtin_amdgcn_s_setprio(1);
            #pragma unroll
            for (int mt = 0; mt < 4; ++mt) {
                const short8 af = lucas_frag(k2 ? (tw[mt] >> 16) : (tw[mt] & 0xffffu));
                #pragma unroll
                for (int nt = 0; nt < 4; ++nt)
                    acc[mh * 4 + mt][nt] = __builtin_amdgcn_mfma_f32_16x16x32_bf16(
                        af, bfr[nt], acc[mh * 4 + mt][nt], 0, 0, 0);
            }
            __builtin_amdgcn_s_setprio(0);
            __builtin_amdgcn_s_barrier();
        }
    }

    // epilogue: D[row=(lane>>4)*4+r][col=lane&15] per 16x16 frag (verified)
    #pragma unroll
    for (int i = 0; i < 8; ++i) {
        #pragma unroll
        for (int nt = 0; nt < 4; ++nt) {
            const int col = n0 + wn * 64 + nt * 16 + l16;
            #pragma unroll
            for (int r = 0; r < 4; ++r) {
                const int row = m0 + wm * 128 + (i >> 2) * 64 + (i & 3) * 16 + quad * 4 + r;
                atomicAdd(&out[(size_t)row * O_DIM + col], acc[i][nt][r]);
            }
        }
    }
}

// ---- fallback (tiny workspace): direct fp32 ----
__global__ __launch_bounds__(256) void naive_kernel(const float* __restrict__ x,
                                                    const float* __restrict__ c,
                                                    float* __restrict__ out) {
    int idx = blockIdx.x * 256 + threadIdx.x;   // one (b,o)
    int b = idx >> 10;
    int o = idx & 1023;
    const float* xb = x + (size_t)b * I_DIM;
    float acc = 0.f;
    for (int i = 0; i < I_DIM; ++i) {
        float t = tanhf(xb[i]);
        float L[8];
        L[0] = 2.0f; L[1] = t;
        #pragma unroll
        for (int d = 2; d < 8; ++d) L[d] = t * L[d - 1] + L[d - 2];
        const float* cc = c + (size_t)i * 8192 + o * 8;
        #pragma unroll
        for (int d = 0; d < 8; ++d) acc += L[d] * cc[d];
    }
    out[idx] = acc;
}

extern "C" void kernel_launch(void* const* d_in, const int* in_sizes, int n_in,
                              void* d_out, int out_size, void* d_ws, size_t ws_size,
                              hipStream_t stream) {
    const float* x      = (const float*)d_in[0];
    const float* coeffs = (const float*)d_in[1];
    float* out = (float*)d_out;

    const size_t btBytes = (size_t)O_DIM * K_DIM * sizeof(unsigned short);   // 16 MiB
    const size_t tBytes  = (size_t)M_DIM * I_DIM * sizeof(unsigned short);   // 16 MiB

    if (ws_size >= btBytes + tBytes) {
        unsigned short* Bt = (unsigned short*)d_ws;
        unsigned short* T  = (unsigned short*)((char*)d_ws + btBytes);

        const int xBlocks = (I_DIM / 64) * (I_DIM / 32);   // 512 transpose tiles
        prep_tr_kernel<<<xBlocks, 256, 0, stream>>>(coeffs, Bt);
        prep_zt_kernel<<<2048, 256, 0, stream>>>(x, T, out);

        dim3 grid(O_DIM / BN, M_DIM / BM, KSPLIT);   // (4, 32, 2) = 256 = 1/CU
        gemm_kernel<<<grid, 512, 0, stream>>>(T, Bt, out);
    } else {
        naive_kernel<<<(M_DIM * O_DIM) / 256, 256, 0, stream>>>(x, coeffs, out);
    }
}

// Round 8
// 251.710 us; speedup vs baseline: 1.2984x; 1.1201x over previous
//
#include <hip/hip_runtime.h>
#include <hip/hip_bf16.h>

// ---------------------------------------------------------------------------
// LucasKANLayer fused: y[b,o] = sum_i sum_d L_d(tanh(x[b,i])) * C[i,o,d]
// R19 = RESTORE verified best (R11 gemm + R12 split prep, measured 245us
// total / 137us gemm, MfmaUtil 47, conflicts 1.05M).
// Session ledger - all structural variations measured and REGRESSED:
//   R13 fat waves 2x64m:          151us, Mfma 40 (occ 18.6)
//   R14 counted vmcnt 4-buf 128²: 151us, Mfma 40 (2 blk/CU)
//   R15 32x32x16 shape:           156us (16.8M bank conflicts)
//   R16 32x32 + fixed swizzle:    150us (conflicts 0 - shape still loses)
//   R17 BN=64 8 blk/CU occ 79%:   228us, Mfma 26 (FETCH 290MB thrash)
//   R18 256² 4-phase deep pipe:   200us, Mfma 29 (VALU-in-cluster starves)
// Mechanism: this problem's A-operand is COMPUTED per step (lucas 6-FMA
// serial chain, 8x data compression). R11's 4 independent blocks/CU of
// mixed MFMA+VALU waves co-schedule (m114) to 47+36=83% combined; every
// pure-GEMM template (role-split setprio, counted-vmcnt lockstep, 256²
// 1 blk/CU) removes the cross-block TLP that hides the VALU chains.
// ---------------------------------------------------------------------------

typedef __attribute__((ext_vector_type(8)))  short  short8;    // bf16x8 MFMA frag
typedef __attribute__((ext_vector_type(4)))  unsigned short ushort4v;
typedef __attribute__((ext_vector_type(8)))  unsigned short ushort8;
typedef __attribute__((ext_vector_type(4)))  float  float4v;
typedef __attribute__((ext_vector_type(4)))  unsigned int uint4v;

#define M_DIM 8192
#define I_DIM 1024
#define O_DIM 1024
#define K_DIM 8192   // I_DIM * 8
#define BM 128
#define BN 128
#define BK 64        // 8 i-values per K-step
#define KSPLIT 2
#define KHALF (K_DIM / KSPLIT)
#define NSTEP (KHALF / BK)   // 64

// round-to-nearest-even fp32 -> bf16 bits (prep kernels)
__device__ __forceinline__ unsigned short f2bf(float f) {
    unsigned int u = __float_as_uint(f);
    u += 0x7FFFu + ((u >> 16) & 1u);
    return (unsigned short)(u >> 16);
}

// ---- P1: zero d_out + tanh->T, grid-stride, NO LDS (full occupancy) ----
// T[b][group g]: slot 2p = t(i=g*8+p), slot 2p+1 = t(i=g*8+p+4): b32 read at
// u16-offset quad*2 gives {lo=t(quad), hi=t(quad+4)}       [R6-verified].
__global__ __launch_bounds__(256) void prep_zt_kernel(const float* __restrict__ x,
                                                      unsigned short* __restrict__ T,
                                                      float* __restrict__ outz) {
    const int nthr = gridDim.x * 256;
    const int gid  = blockIdx.x * 256 + threadIdx.x;

    // zero out: M*O floats = 2,097,152 float4 chunks
    const int zN = (M_DIM * O_DIM) / 4;
    const float4v z = {0.f, 0.f, 0.f, 0.f};
    for (int i = gid; i < zN; i += nthr)
        *(float4v*)(outz + (size_t)i * 4) = z;

    // tanh: M*I / 8 = 1,048,576 chunks
    const int tN = (M_DIM * I_DIM) / 8;
    for (int i = gid; i < tN; i += nthr) {
        const size_t idx = (size_t)i * 8;
        float4v v0 = *(const float4v*)(x + idx);
        float4v v1 = *(const float4v*)(x + idx + 4);
        unsigned short t[8];
        t[0] = f2bf(tanhf(v0[0])); t[1] = f2bf(tanhf(v0[1]));
        t[2] = f2bf(tanhf(v0[2])); t[3] = f2bf(tanhf(v0[3]));
        t[4] = f2bf(tanhf(v1[0])); t[5] = f2bf(tanhf(v1[1]));
        t[6] = f2bf(tanhf(v1[2])); t[7] = f2bf(tanhf(v1[3]));
        ushort8 o;
        #pragma unroll
        for (int p = 0; p < 4; ++p) { o[2 * p] = t[p]; o[2 * p + 1] = t[p + 4]; }
        *(ushort8*)(T + idx) = o;
    }
}

// ---- P2: B transpose via LDS (tile 64 i x 32 o, coalesced R+W) ----
// Bt[o][i*8+d] = bf16(coeffs[i][o][d])                     [R9-verified].
__global__ __launch_bounds__(256) void prep_tr_kernel(const float* __restrict__ c,
                                                      unsigned short* __restrict__ Bt) {
    __shared__ unsigned short S[32][64 * 8 + 8];
    const int tid = threadIdx.x;
    const int tb  = blockIdx.x;                    // 0..511
    const int i0 = (tb >> 5) * 64;
    const int o0 = (tb & 31) * 32;
    #pragma unroll 4
    for (int p = 0; p < 16; ++p) {
        const int il = p * 4 + (tid >> 6);
        const int e  = (tid & 63) * 4;
        const float* src = c + (size_t)(i0 + il) * 8192 + o0 * 8 + e;
        float4v v = *(const float4v*)src;
        ushort4v u;
        u[0] = f2bf(v[0]); u[1] = f2bf(v[1]); u[2] = f2bf(v[2]); u[3] = f2bf(v[3]);
        *(ushort4v*)&S[e >> 3][il * 8 + (e & 7)] = u;
    }
    __syncthreads();
    #pragma unroll 4
    for (int q = 0; q < 16; ++q) {
        const int ol = q * 2 + (tid >> 7);
        const int ch = (tid & 127) * 4;
        ushort4v u = *(const ushort4v*)&S[ol][ch];
        *(ushort4v*)(Bt + (size_t)(o0 + ol) * K_DIM + i0 * 8 + ch) = u;
    }
}

// Lucas A-fragment {2, t, L2..L7} packed bf16x8 from bf16 t-bits tb (low 16).
__device__ __forceinline__ short8 lucas_frag(unsigned int tb) {
    const float t = __uint_as_float(tb << 16);
    const float L2v = fmaf(t, t, 2.0f);
    const float L3v = fmaf(t, L2v, t);
    const float L4v = fmaf(t, L3v, L2v);
    const float L5v = fmaf(t, L4v, L3v);
    const float L6v = fmaf(t, L5v, L4v);
    const float L7v = fmaf(t, L6v, L5v);
    union { uint4v u; short8 s; } r;
#if __has_builtin(__builtin_amdgcn_cvt_pk_bf16_f32)
    {
        auto p0 = __builtin_amdgcn_cvt_pk_bf16_f32(2.0f, t);
        auto p1 = __builtin_amdgcn_cvt_pk_bf16_f32(L2v, L3v);
        auto p2 = __builtin_amdgcn_cvt_pk_bf16_f32(L4v, L5v);
        auto p3 = __builtin_amdgcn_cvt_pk_bf16_f32(L6v, L7v);
        __builtin_memcpy(&r.u[0], &p0, 4);
        __builtin_memcpy(&r.u[1], &p1, 4);
        __builtin_memcpy(&r.u[2], &p2, 4);
        __builtin_memcpy(&r.u[3], &p3, 4);
    }
#else
    {
        r.u[0] = 0x4000u | (tb << 16);
        r.u[1] = __builtin_amdgcn_perm(__float_as_uint(L3v), __float_as_uint(L2v), 0x07060302);
        r.u[2] = __builtin_amdgcn_perm(__float_as_uint(L5v), __float_as_uint(L4v), 0x07060302);
        r.u[3] = __builtin_amdgcn_perm(__float_as_uint(L7v), __float_as_uint(L6v), 0x07060302);
    }
#endif
    return r.s;
}

// ---- fused GEMM: out[m][n] += sum_{k half} A[m][k] * Bt[n][k] ----
// wave tile 32m x 128n: wave w owns m rows [w*32, w*32+32), all 128 n.
// BYTE-IDENTICAL to R11 (verified 137us, MfmaUtil 47%).
__global__ __launch_bounds__(256, 4) void gemm_kernel(const unsigned short* __restrict__ T,
                                                      const unsigned short* __restrict__ Bt,
                                                      float* __restrict__ out) {
    __shared__ unsigned short Bs[2][BN * BK];   // 32 KB, XOR-swizzled, dbuf
    __shared__ unsigned short Ts[2][BM * 8];    // 4 KB, dbuf (permuted 8-groups)

    const int tid  = threadIdx.x;
    const int lane = tid & 63;
    const int wave = tid >> 6;
    const int n0 = blockIdx.x * BN;        // x = n-panel (8): XCD = linear%8 = x
    const int m0 = blockIdx.y * BM;        // y = m (64)
    const int k0 = blockIdx.z * KHALF;     // z = K half (2)

    const int wm0  = wave * 32;            // wave tile 32m x 128n
    const int l16  = lane & 15;
    const int quad = lane >> 4;

    const int srow   = lane >> 3;          // staging: 0..7
    const int il     = lane & 7;
    const int gchunk = il ^ srow;          // XOR-swizzled global 16B chunk

    float4v acc[2][8];
    const float4v zero = {0.f, 0.f, 0.f, 0.f};
    #pragma unroll
    for (int a = 0; a < 2; ++a)
        #pragma unroll
        for (int b = 0; b < 8; ++b) acc[a][b] = zero;

    // stage one K-step: B 4 insts/wave (8 rows each, 128 total), T wave<2
    auto stage = [&](int buf, int kt) {
        #pragma unroll
        for (int r = 0; r < 4; ++r) {
            const int rowb = r * 32 + wave * 8;
            const unsigned short* gB = Bt + (size_t)(n0 + rowb + srow) * K_DIM + kt + gchunk * 8;
            __builtin_amdgcn_global_load_lds(
                (const __attribute__((address_space(1))) unsigned int*)gB,
                (__attribute__((address_space(3))) unsigned int*)&Bs[buf][rowb * BK], 16, 0, 0);
        }
        if (wave < 2) {
            const unsigned short* gT = T + (size_t)(m0 + wave * 64 + lane) * I_DIM + kt / 8;
            __builtin_amdgcn_global_load_lds(
                (const __attribute__((address_space(1))) unsigned int*)gT,
                (__attribute__((address_space(3))) unsigned int*)&Ts[buf][wave * 64 * 8], 16, 0, 0);
        }
    };

    stage(0, k0);
    __syncthreads();

    int cur = 0;
    for (int s = 0; s < NSTEP; ++s) {
        const int nxt = cur ^ 1;
        if (s + 1 < NSTEP) stage(nxt, k0 + (s + 1) * BK);

        // t-words: one b32 per m-tile {lo=t(quad)->k2=0, hi=t(quad+4)->k2=1}
        unsigned int tw[2];
        #pragma unroll
        for (int tt = 0; tt < 2; ++tt)
            tw[tt] = *(const unsigned int*)&Ts[cur][(wm0 + tt * 16 + l16) * 8 + quad * 2];

        #pragma unroll
        for (int k2 = 0; k2 < 2; ++k2) {
            short8 af[2];
            af[0] = lucas_frag(k2 ? (tw[0] >> 16) : (tw[0] & 0xffffu));
            af[1] = lucas_frag(k2 ? (tw[1] >> 16) : (tw[1] & 0xffffu));
            #pragma unroll
            for (int g = 0; g < 2; ++g) {          // n-halves: <=4 live b-frags
                short8 bfr[4];
                #pragma unroll
                for (int j = 0; j < 4; ++j) {
                    const int brow = (g * 4 + j) * 16 + l16;
                    bfr[j] = *(const short8*)&Bs[cur][brow * BK + (((k2 * 4 + quad) ^ (l16 & 7)) * 8)];
                }
                #pragma unroll
                for (int tt = 0; tt < 2; ++tt)
                    #pragma unroll
                    for (int j = 0; j < 4; ++j)
                        acc[tt][g * 4 + j] = __builtin_amdgcn_mfma_f32_16x16x32_bf16(
                            af[tt], bfr[j], acc[tt][g * 4 + j], 0, 0, 0);
            }
        }

        __syncthreads();   // drains prefetch + protects Bs/Ts swap
        cur = nxt;
    }

    // epilogue: D[row=(lane>>4)*4+r][col=lane&15] (verified R1-R9)
    #pragma unroll
    for (int tt = 0; tt < 2; ++tt) {
        #pragma unroll
        for (int tn = 0; tn < 8; ++tn) {
            const int col = n0 + tn * 16 + l16;
            #pragma unroll
            for (int r = 0; r < 4; ++r) {
                const int row = m0 + wm0 + tt * 16 + quad * 4 + r;
                atomicAdd(&out[(size_t)row * O_DIM + col], acc[tt][tn][r]);
            }
        }
    }
}

// ---- fallback (tiny workspace): direct fp32 ----
__global__ __launch_bounds__(256) void naive_kernel(const float* __restrict__ x,
                                                    const float* __restrict__ c,
                                                    float* __restrict__ out) {
    int idx = blockIdx.x * 256 + threadIdx.x;   // one (b,o)
    int b = idx >> 10;
    int o = idx & 1023;
    const float* xb = x + (size_t)b * I_DIM;
    float acc = 0.f;
    for (int i = 0; i < I_DIM; ++i) {
        float t = tanhf(xb[i]);
        float L[8];
        L[0] = 2.0f; L[1] = t;
        #pragma unroll
        for (int d = 2; d < 8; ++d) L[d] = t * L[d - 1] + L[d - 2];
        const float* cc = c + (size_t)i * 8192 + o * 8;
        #pragma unroll
        for (int d = 0; d < 8; ++d) acc += L[d] * cc[d];
    }
    out[idx] = acc;
}

extern "C" void kernel_launch(void* const* d_in, const int* in_sizes, int n_in,
                              void* d_out, int out_size, void* d_ws, size_t ws_size,
                              hipStream_t stream) {
    const float* x      = (const float*)d_in[0];
    const float* coeffs = (const float*)d_in[1];
    float* out = (float*)d_out;

    const size_t btBytes = (size_t)O_DIM * K_DIM * sizeof(unsigned short);   // 16 MiB
    const size_t tBytes  = (size_t)M_DIM * I_DIM * sizeof(unsigned short);   // 16 MiB

    if (ws_size >= btBytes + tBytes) {
        unsigned short* Bt = (unsigned short*)d_ws;
        unsigned short* T  = (unsigned short*)((char*)d_ws + btBytes);

        const int xBlocks = (I_DIM / 64) * (I_DIM / 32);   // 512 transpose tiles
        prep_tr_kernel<<<xBlocks, 256, 0, stream>>>(coeffs, Bt);
        prep_zt_kernel<<<2048, 256, 0, stream>>>(x, T, out);

        dim3 grid(O_DIM / BN, M_DIM / BM, KSPLIT);   // (8, 64, 2): XCD = x
        gemm_kernel<<<grid, 256, 0, stream>>>(T, Bt, out);
    } else {
        naive_kernel<<<(M_DIM * O_DIM) / 256, 256, 0, stream>>>(x, coeffs, out);
    }
}